// Round 1
// baseline (355.785 us; speedup 1.0000x reference)
//
#include <hip/hip_runtime.h>

#define NPART 32
#define DIM   256
#define BATCH 8192

// ---- workspace offsets (float units) ----
#define OFF_DZT   0u          // [8192][32] dzdy transposed
#define OFF_S     262144u     // [8192] s[b]
#define OFF_DWP   270336u     // [64][32][256] dW partials
#define OFF_WG    794624u     // [32][256] W_grads
#define OFF_COVP  802816u     // [16][256][256] cov partials
#define OFF_H     1851392u    // [256][256]
#define OFF_XA    1916928u    // [256][256] NS buffer A
#define OFF_XB    1982464u    // [256][256] NS buffer B
#define OFF_U     2048000u    // [256][256] NS temp
#define OFF_SVGD  2113536u    // [32][256]
#define OFF_LLP   2121728u    // 64 doubles (128 floats)
#define OFF_ACCP  2121856u    // 64 floats
#define OFF_TAU   2121920u    // 1 uint (gershgorin bound bits)
// total ~8.5 MB of d_ws

__device__ __forceinline__ float dot4(float4 a, float4 b) {
  return a.x*b.x + a.y*b.y + a.z*b.z + a.w*b.w;
}

// ---------------------------------------------------------------------------
// K1: z = W @ X^T, p, dzdy, per-b stats (s, ypred->ll/acc partials), dzdyT out
// grid 64 x 256 threads; block handles 128 batch rows (4 tiles of 32)
// ---------------------------------------------------------------------------
__global__ __launch_bounds__(256) void k_zstats(
    const float4* __restrict__ X4, const float* __restrict__ y,
    const float4* __restrict__ W4,
    float* __restrict__ dzdyT, float* __restrict__ s_ws,
    double* __restrict__ llpart, float* __restrict__ accpart)
{
  __shared__ float4 Wl[32][65];
  __shared__ float4 Xl[32][65];
  __shared__ double llred[16];
  __shared__ float  accred[16];
  const int t = threadIdx.x, blk = blockIdx.x;

  #pragma unroll
  for (int i = 0; i < 8; ++i) { int idx = t + i*256; Wl[idx>>6][idx&63] = W4[idx]; }

  const int nb = t & 15, bs = t >> 4;
  const int n0 = nb, n1 = nb + 16;
  double llacc = 0.0; float accacc = 0.f;

  for (int tile = 0; tile < 4; ++tile) {
    const int base = blk*128 + tile*32;
    __syncthreads();
    #pragma unroll
    for (int i = 0; i < 8; ++i) {
      int idx = t + i*256;
      Xl[idx>>6][idx&63] = X4[(base + (idx>>6))*64 + (idx&63)];
    }
    __syncthreads();
    const int r0 = bs, r1 = bs + 16;
    float z00=0.f, z01=0.f, z10=0.f, z11=0.f;
    #pragma unroll 8
    for (int c = 0; c < 64; ++c) {
      float4 wa = Wl[n0][c], wb = Wl[n1][c];
      float4 xa = Xl[r0][c], xb = Xl[r1][c];
      z00 += dot4(wa, xa); z01 += dot4(wa, xb);
      z10 += dot4(wb, xa); z11 += dot4(wb, xb);
    }
    const int b0 = base + bs, b1 = base + bs + 16;
    const float y0 = y[b0], y1 = y[b1];

    float p00 = 1.f/(1.f+__expf(-z00));  // fast exp ~1ulp-ish; sigmoid well conditioned
    float p01 = 1.f/(1.f+__expf(-z01));
    float p10 = 1.f/(1.f+__expf(-z10));
    float p11 = 1.f/(1.f+__expf(-z11));
    // use precise expf to stay close to reference
    p00 = 1.f/(1.f+expf(-z00)); p01 = 1.f/(1.f+expf(-z01));
    p10 = 1.f/(1.f+expf(-z10)); p11 = 1.f/(1.f+expf(-z11));

    auto dzf = [](float p, float yv) {
      float pq = p - p*p;
      return pq*(yv - p)/(pq + 1e-8f);
    };
    float dz00 = dzf(p00, y0), dz01 = dzf(p01, y1);
    float dz10 = dzf(p10, y0), dz11 = dzf(p11, y1);

    // reductions over 32 particles: local fold (n0+n1) then 16-lane xor tree
    float sp0 = p00 + p10, sp1 = p01 + p11;
    float sd0 = dz00 + dz10, sd1 = dz01 + dz11;
    #pragma unroll
    for (int m = 8; m >= 1; m >>= 1) {
      sp0 += __shfl_xor(sp0, m); sp1 += __shfl_xor(sp1, m);
      sd0 += __shfl_xor(sd0, m); sd1 += __shfl_xor(sd1, m);
    }
    const float m0 = sd0*(1.f/32.f), m1 = sd1*(1.f/32.f);
    float q0 = (dz00-m0)*(dz00-m0) + (dz10-m0)*(dz10-m0);
    float q1 = (dz01-m1)*(dz01-m1) + (dz11-m1)*(dz11-m1);
    #pragma unroll
    for (int m = 8; m >= 1; m >>= 1) {
      q0 += __shfl_xor(q0, m); q1 += __shfl_xor(q1, m);
    }

    dzdyT[b0*32 + n0] = dz00; dzdyT[b0*32 + n1] = dz10;
    dzdyT[b1*32 + n0] = dz01; dzdyT[b1*32 + n1] = dz11;

    if (nb == 0) {
      s_ws[b0] = q0; s_ws[b1] = q1;
      float yp0 = sp0*(1.f/32.f), yp1 = sp1*(1.f/32.f);
      llacc += (double)(y0*logf(yp0+1e-3f) + (1.f-y0)*logf(1.f-yp0+1e-3f));
      llacc += (double)(y1*logf(yp1+1e-3f) + (1.f-y1)*logf(1.f-yp1+1e-3f));
      accacc += ((y0 > 0.5f) == (yp0 > 0.5f)) ? 1.f : 0.f;
      accacc += ((y1 > 0.5f) == (yp1 > 0.5f)) ? 1.f : 0.f;
    }
  }
  __syncthreads();
  if (nb == 0) { llred[bs] = llacc; accred[bs] = accacc; }
  __syncthreads();
  if (t == 0) {
    double L = 0.0; float A = 0.f;
    for (int i = 0; i < 16; ++i) { L += llred[i]; A += accred[i]; }
    llpart[blk] = L; accpart[blk] = A;
  }
}

// ---------------------------------------------------------------------------
// K2: dW partials: dWpart[blk][n][d] = sum_{b in chunk} dzdyT[b][n] * X[b][d]
// grid 64 x 256; chunk = 128 rows (4 sub-chunks of 32 staged)
// ---------------------------------------------------------------------------
__global__ __launch_bounds__(256) void k_dw(
    const float4* __restrict__ X4, const float4* __restrict__ dzT4,
    float4* __restrict__ dWp4)
{
  __shared__ float4 Xl[32][65];
  __shared__ float  dzl[32][36];
  const int t = threadIdx.x, blk = blockIdx.x;
  const int n = t >> 3, c = t & 7;
  float4 acc[8];
  #pragma unroll
  for (int m = 0; m < 8; ++m) acc[m] = make_float4(0.f,0.f,0.f,0.f);

  for (int sub = 0; sub < 4; ++sub) {
    const int base = blk*128 + sub*32;
    __syncthreads();
    #pragma unroll
    for (int i = 0; i < 8; ++i) {
      int idx = t + i*256;
      Xl[idx>>6][idx&63] = X4[(base + (idx>>6))*64 + (idx&63)];
    }
    { // stage dzdyT chunk: 32 rows x 32 n = 256 float4
      int row = t >> 3, c4 = t & 7;
      float4 dv = dzT4[(base+row)*8 + c4];
      dzl[row][c4*4+0] = dv.x; dzl[row][c4*4+1] = dv.y;
      dzl[row][c4*4+2] = dv.z; dzl[row][c4*4+3] = dv.w;
    }
    __syncthreads();
    #pragma unroll 4
    for (int b = 0; b < 32; ++b) {
      float dzv = dzl[b][n];
      #pragma unroll
      for (int m = 0; m < 8; ++m) {
        float4 xv = Xl[b][c + 8*m];
        acc[m].x += dzv*xv.x; acc[m].y += dzv*xv.y;
        acc[m].z += dzv*xv.z; acc[m].w += dzv*xv.w;
      }
    }
  }
  #pragma unroll
  for (int m = 0; m < 8; ++m)
    dWp4[blk*2048 + n*64 + c + 8*m] = acc[m];
}

// ---------------------------------------------------------------------------
// K3: finalize W_grads = sum_k dWpart - W  (N_TRAIN/BATCH == 1 exactly);
//     block 32: ll/acc scalars + tau init
// ---------------------------------------------------------------------------
__global__ __launch_bounds__(256) void k_finalize(
    const float* __restrict__ dWpart, const float* __restrict__ W,
    float* __restrict__ Wg, const double* __restrict__ llpart,
    const float* __restrict__ accpart, float* __restrict__ out,
    unsigned int* __restrict__ tau_bits)
{
  const int blk = blockIdx.x, t = threadIdx.x;
  if (blk < 32) {
    float sum = 0.f;
    #pragma unroll 8
    for (int k = 0; k < 64; ++k) sum += dWpart[k*8192 + blk*256 + t];
    Wg[blk*256 + t] = sum - W[blk*256 + t];
  } else {
    if (t == 0) {
      double L = 0.0;
      for (int k = 0; k < 64; ++k) L += llpart[k];
      out[0] = (float)(L / 8192.0);
    } else if (t == 1) {
      float A = 0.f;
      for (int k = 0; k < 64; ++k) A += accpart[k];
      out[1] = A / 8192.f;
    } else if (t == 2) {
      *tau_bits = 0u;
    }
  }
}

// ---------------------------------------------------------------------------
// K4: cov partials: weighted SYRK  covpart[z] = sum_{b in chunk} s[b] X[b,dT] X[b,eT]
// grid (4,4,16) x 256; 64x64 tile per block, K-chunk 512
// ---------------------------------------------------------------------------
__global__ __launch_bounds__(256) void k_cov(
    const float4* __restrict__ X4, const float* __restrict__ s_ws,
    float* __restrict__ covpart)
{
  __shared__ float4 Ad[32][17];
  __shared__ float4 Ae[32][17];
  const int t = threadIdx.x;
  const int dt = blockIdx.x*16;   // f4 units (64 floats)
  const int et = blockIdx.y*16;
  const int kb = blockIdx.z*512;
  const int tx = t & 15, ty = t >> 4;
  float acc[4][4];
  #pragma unroll
  for (int i = 0; i < 4; ++i)
    #pragma unroll
    for (int j = 0; j < 4; ++j) acc[i][j] = 0.f;

  for (int sub = 0; sub < 16; ++sub) {
    const int b0 = kb + sub*32;
    __syncthreads();
    #pragma unroll
    for (int i = 0; i < 2; ++i) {
      int idx = t + i*256; int row = idx>>4, c4 = idx&15;
      float sv = s_ws[b0+row];
      float4 xv = X4[(b0+row)*64 + dt + c4];
      Ad[row][c4] = make_float4(xv.x*sv, xv.y*sv, xv.z*sv, xv.w*sv);
      Ae[row][c4] = X4[(b0+row)*64 + et + c4];
    }
    __syncthreads();
    #pragma unroll 4
    for (int b = 0; b < 32; ++b) {
      float4 a = Ad[b][tx], e = Ae[b][ty];
      acc[0][0] += a.x*e.x; acc[0][1] += a.x*e.y; acc[0][2] += a.x*e.z; acc[0][3] += a.x*e.w;
      acc[1][0] += a.y*e.x; acc[1][1] += a.y*e.y; acc[1][2] += a.y*e.z; acc[1][3] += a.y*e.w;
      acc[2][0] += a.z*e.x; acc[2][1] += a.z*e.y; acc[2][2] += a.z*e.z; acc[2][3] += a.z*e.w;
      acc[3][0] += a.w*e.x; acc[3][1] += a.w*e.y; acc[3][2] += a.w*e.z; acc[3][3] += a.w*e.w;
    }
  }
  float4* cp4 = (float4*)(covpart + blockIdx.z*65536);
  #pragma unroll
  for (int i = 0; i < 4; ++i) {
    int gd = dt*4 + tx*4 + i;
    cp4[gd*64 + et + ty] = make_float4(acc[i][0], acc[i][1], acc[i][2], acc[i][3]);
  }
}

// ---------------------------------------------------------------------------
// K5: H = covsum/(32*8192) + 0.01 I ; tau = max_i sum_j |H_ij| via atomicMax
// grid 256 x 256
// ---------------------------------------------------------------------------
__global__ __launch_bounds__(256) void k_H(
    const float* __restrict__ covpart, float* __restrict__ H,
    unsigned int* __restrict__ tau_bits)
{
  __shared__ float red[4];
  const int d = blockIdx.x, t = threadIdx.x;
  float sum = 0.f;
  #pragma unroll
  for (int k = 0; k < 16; ++k) sum += covpart[k*65536 + d*256 + t];
  float h = sum * (1.f/262144.f) + ((d == t) ? 0.01f : 0.f);
  H[d*256 + t] = h;
  float a = fabsf(h);
  #pragma unroll
  for (int m = 32; m >= 1; m >>= 1) a += __shfl_xor(a, m);
  if ((t & 63) == 0) red[t >> 6] = a;
  __syncthreads();
  if (t == 0) {
    float r = red[0] + red[1] + red[2] + red[3];
    atomicMax(tau_bits, __float_as_uint(r));   // order-independent -> deterministic
  }
}

// K6: X0 = 2/(tau+0.01) * I
__global__ __launch_bounds__(256) void k_nsinit(
    const unsigned int* __restrict__ tau_bits, float* __restrict__ Xa)
{
  const float tau = __uint_as_float(*tau_bits);
  const float c = 2.f/(tau + 0.01f);
  const int d = blockIdx.x, t = threadIdx.x;
  Xa[d*256 + t] = (d == t) ? c : 0.f;
}

// ---------------------------------------------------------------------------
// gemm256: mode 0: C = A@B ; mode 1: C = 2*Xarg - A@B   (all 256x256)
// grid (8,8) x 256; 32x32 tile, 2x2 micro-tile
// ---------------------------------------------------------------------------
__global__ __launch_bounds__(256) void gemm256(
    const float* __restrict__ A, const float* __restrict__ B,
    const float* __restrict__ Xarg, float* __restrict__ C, int mode)
{
  __shared__ float As[32][33];
  __shared__ float Bs[32][33];
  const int t = threadIdx.x;
  const int i0 = blockIdx.x*32, j0 = blockIdx.y*32;
  const int ti = t & 15, tj = t >> 4;
  const int srow = t >> 3, sc4 = t & 7;
  const float4* A4 = (const float4*)A;
  const float4* B4 = (const float4*)B;
  float acc00=0.f, acc01=0.f, acc10=0.f, acc11=0.f;

  for (int k0 = 0; k0 < 8; ++k0) {
    __syncthreads();
    float4 av = A4[(i0+srow)*64 + k0*8 + sc4];
    float4 bv = B4[(k0*32+srow)*64 + (j0>>2) + sc4];
    As[srow][sc4*4+0]=av.x; As[srow][sc4*4+1]=av.y; As[srow][sc4*4+2]=av.z; As[srow][sc4*4+3]=av.w;
    Bs[srow][sc4*4+0]=bv.x; Bs[srow][sc4*4+1]=bv.y; Bs[srow][sc4*4+2]=bv.z; Bs[srow][sc4*4+3]=bv.w;
    __syncthreads();
    #pragma unroll
    for (int kk = 0; kk < 32; ++kk) {
      float a0 = As[2*ti][kk], a1 = As[2*ti+1][kk];
      float b0 = Bs[kk][2*tj], b1 = Bs[kk][2*tj+1];
      acc00 += a0*b0; acc01 += a0*b1; acc10 += a1*b0; acc11 += a1*b1;
    }
  }
  const int gi = i0 + 2*ti, gj = j0 + 2*tj;
  if (mode == 0) {
    C[gi*256+gj]       = acc00; C[gi*256+gj+1]     = acc01;
    C[(gi+1)*256+gj]   = acc10; C[(gi+1)*256+gj+1] = acc11;
  } else {
    C[gi*256+gj]       = 2.f*Xarg[gi*256+gj]       - acc00;
    C[gi*256+gj+1]     = 2.f*Xarg[gi*256+gj+1]     - acc01;
    C[(gi+1)*256+gj]   = 2.f*Xarg[(gi+1)*256+gj]   - acc10;
    C[(gi+1)*256+gj+1] = 2.f*Xarg[(gi+1)*256+gj+1] - acc11;
  }
}

// ---------------------------------------------------------------------------
// K7: RBF kernel + median bandwidth + svgd_grad. single block, 1024 threads
// ---------------------------------------------------------------------------
__global__ __launch_bounds__(1024) void k_rbf(
    const float4* __restrict__ W4, const float4* __restrict__ Wg4,
    float* __restrict__ svgd_ws, float* __restrict__ out)
{
  __shared__ float4 Wl[32][65];
  __shared__ float4 Wgl[32][65];
  __shared__ float pd[32][33];
  __shared__ float sb[1024];
  __shared__ float kx[32][33];
  __shared__ float sumk[32];
  __shared__ float hsh;
  const int t = threadIdx.x;

  #pragma unroll
  for (int i = 0; i < 2; ++i) {
    int idx = t + i*1024;
    Wl[idx>>6][idx&63]  = W4[idx];
    Wgl[idx>>6][idx&63] = Wg4[idx];
  }
  __syncthreads();

  const int i = t >> 5, j = t & 31;
  float d2 = 0.f;
  #pragma unroll 8
  for (int c = 0; c < 64; ++c) {
    float4 a = Wl[i][c], b = Wl[j][c];
    float dx=a.x-b.x, dy=a.y-b.y, dz=a.z-b.z, dw=a.w-b.w;
    d2 += dx*dx + dy*dy + dz*dz + dw*dw;
  }
  pd[i][j] = d2;
  sb[t] = d2;
  __syncthreads();

  // bitonic sort of the 1024 squared distances (exact median)
  for (int k = 2; k <= 1024; k <<= 1) {
    for (int jj = k >> 1; jj > 0; jj >>= 1) {
      int ixj = t ^ jj;
      if (ixj > t) {
        float a = sb[t], b = sb[ixj];
        bool up = ((t & k) == 0);
        if ((a > b) == up) { sb[t] = b; sb[ixj] = a; }
      }
      __syncthreads();
    }
  }
  if (t == 0) hsh = 0.5f*(sb[511] + sb[512]) / logf(33.0f);
  __syncthreads();
  const float h = hsh;

  float kv = expf(-pd[i][j]/h);
  kx[i][j] = kv;
  float sk = kv;
  #pragma unroll
  for (int m = 16; m >= 1; m >>= 1) sk += __shfl_xor(sk, m);
  if (j == 0) sumk[i] = sk;
  __syncthreads();

  const float c2 = 2.f/h;
  #pragma unroll
  for (int rep = 0; rep < 2; ++rep) {
    int o = t + rep*1024;
    int oi = o >> 6, oc = o & 63;
    float4 acc = make_float4(0.f,0.f,0.f,0.f);
    #pragma unroll 4
    for (int jj = 0; jj < 32; ++jj) {
      float kvv = kx[oi][jj];
      float4 wg = Wgl[jj][oc], w = Wl[jj][oc];
      acc.x += kvv*(wg.x - c2*w.x);
      acc.y += kvv*(wg.y - c2*w.y);
      acc.z += kvv*(wg.z - c2*w.z);
      acc.w += kvv*(wg.w - c2*w.w);
    }
    float4 wi = Wl[oi][oc];
    float s = c2 * sumk[oi];
    acc.x = (acc.x + s*wi.x) * (1.f/32.f);
    acc.y = (acc.y + s*wi.y) * (1.f/32.f);
    acc.z = (acc.z + s*wi.z) * (1.f/32.f);
    acc.w = (acc.w + s*wi.w) * (1.f/32.f);
    ((float4*)svgd_ws)[oi*64 + oc] = acc;
    int base = 2 + oi*256 + oc*4;       // d_out+2 is only 8B aligned -> scalar stores
    out[base+0] = acc.x; out[base+1] = acc.y; out[base+2] = acc.z; out[base+3] = acc.w;
  }
}

// ---------------------------------------------------------------------------
// K8: kfac = svgd @ Hinv  -> out[2+8192 ...]
// ---------------------------------------------------------------------------
__global__ __launch_bounds__(256) void k_kfac(
    const float* __restrict__ svgd, const float* __restrict__ Hinv,
    float* __restrict__ out)
{
  __shared__ float sv[256];
  const int i = blockIdx.x, t = threadIdx.x;
  sv[t] = svgd[i*256 + t];
  __syncthreads();
  float acc = 0.f;
  #pragma unroll 8
  for (int k = 0; k < 256; ++k) acc += sv[k] * Hinv[k*256 + t];
  out[2 + 8192 + i*256 + t] = acc;
}

// ---------------------------------------------------------------------------
extern "C" void kernel_launch(void* const* d_in, const int* in_sizes, int n_in,
                              void* d_out, int out_size, void* d_ws, size_t ws_size,
                              hipStream_t stream) {
  (void)in_sizes; (void)n_in; (void)out_size; (void)ws_size;
  const float* X = (const float*)d_in[0];
  const float* y = (const float*)d_in[1];
  const float* W = (const float*)d_in[2];
  float* out = (float*)d_out;
  float* ws  = (float*)d_ws;

  float* dzT   = ws + OFF_DZT;
  float* s_ws  = ws + OFF_S;
  float* dWp   = ws + OFF_DWP;
  float* Wg    = ws + OFF_WG;
  float* covp  = ws + OFF_COVP;
  float* H     = ws + OFF_H;
  float* XA    = ws + OFF_XA;
  float* XB    = ws + OFF_XB;
  float* U     = ws + OFF_U;
  float* svgd  = ws + OFF_SVGD;
  double* llp  = (double*)(ws + OFF_LLP);
  float* accp  = ws + OFF_ACCP;
  unsigned int* tau = (unsigned int*)(ws + OFF_TAU);

  k_zstats<<<64, 256, 0, stream>>>((const float4*)X, y, (const float4*)W,
                                   dzT, s_ws, llp, accp);
  k_dw<<<64, 256, 0, stream>>>((const float4*)X, (const float4*)dzT, (float4*)dWp);
  k_finalize<<<33, 256, 0, stream>>>(dWp, W, Wg, llp, accp, out, tau);
  k_cov<<<dim3(4,4,16), 256, 0, stream>>>((const float4*)X, s_ws, covp);
  k_H<<<256, 256, 0, stream>>>(covp, H, tau);
  k_nsinit<<<256, 256, 0, stream>>>(tau, XA);

  float* Xc = XA; float* Xn = XB;
  for (int it = 0; it < 12; ++it) {
    gemm256<<<dim3(8,8), 256, 0, stream>>>(H, Xc, nullptr, U, 0);   // U = H@Xc
    gemm256<<<dim3(8,8), 256, 0, stream>>>(Xc, U, Xc, Xn, 1);       // Xn = 2Xc - Xc@U
    float* tmp = Xc; Xc = Xn; Xn = tmp;
  }

  k_rbf<<<1, 1024, 0, stream>>>((const float4*)W, (const float4*)Wg, svgd, out);
  k_kfac<<<32, 256, 0, stream>>>(svgd, Xc, out);
}

// Round 2
// 174.202 us; speedup vs baseline: 2.0424x; 2.0424x over previous
//
#include <hip/hip_runtime.h>

#define NPART 32
#define DIM   256
#define BATCH 8192

// ---- workspace offsets (float units) ----
#define OFF_S     0u          // [8192] s[b]
#define OFF_DWP   8192u       // [256][32][256] dW partials (8MB)
#define OFF_WG    2105344u    // [32][256] W_grads
#define OFF_COVP  2113536u    // [32][256][256] cov partials (8MB, upper tiles only)
#define OFF_H     4210688u    // [256][256]
#define OFF_EA    4276224u    // [256][256] NS E ping
#define OFF_EB    4341760u    // [256][256] NS E pong
#define OFF_XA    4407296u    // [256][256] NS X ping
#define OFF_XB    4472832u    // [256][256] NS X pong
#define OFF_SVGD  4538368u    // [32][256]
#define OFF_LLP   4546560u    // 256 doubles (512 floats)
#define OFF_ACCP  4547072u    // 256 floats
#define OFF_TAU   4547328u    // 1 uint
// total ~18.2 MB of d_ws (ws_size ~256MB per observed poison fill)

__constant__ int c_pi[10] = {0,0,0,0,1,1,1,2,2,3};
__constant__ int c_pj[10] = {0,1,2,3,1,2,3,2,3,3};

__device__ __forceinline__ float dot4(float4 a, float4 b) {
  return a.x*b.x + a.y*b.y + a.z*b.z + a.w*b.w;
}

// ---------------------------------------------------------------------------
// K1 fused: z = W@X^T -> p -> dzdy -> {s[b], ll/acc partials, dW partials}
// grid 256 x 256 threads; each block owns 32 batch rows; X tile reused in LDS
// ---------------------------------------------------------------------------
__global__ __launch_bounds__(256) void k_fused1(
    const float4* __restrict__ X4, const float* __restrict__ y,
    const float4* __restrict__ W4,
    float* __restrict__ s_ws, float4* __restrict__ dWp4,
    double* __restrict__ llpart, float* __restrict__ accpart)
{
  __shared__ float4 Wl[32][65];
  __shared__ float4 Xl[32][65];
  __shared__ float  dzl[32][36];
  __shared__ double llred[16];
  __shared__ float  accred[16];
  const int t = threadIdx.x, blk = blockIdx.x;
  const int base = blk*32;

  #pragma unroll
  for (int i = 0; i < 8; ++i) { int idx = t + i*256; Wl[idx>>6][idx&63] = W4[idx]; }
  #pragma unroll
  for (int i = 0; i < 8; ++i) {
    int idx = t + i*256;
    Xl[idx>>6][idx&63] = X4[(base + (idx>>6))*64 + (idx&63)];
  }
  __syncthreads();

  const int nb = t & 15, bs = t >> 4;
  const int n0 = nb, n1 = nb + 16;

  float z00=0.f, z01=0.f, z10=0.f, z11=0.f;
  #pragma unroll 8
  for (int c = 0; c < 64; ++c) {
    float4 wa = Wl[n0][c], wb = Wl[n1][c];
    float4 xa = Xl[bs][c], xb = Xl[bs+16][c];
    z00 += dot4(wa, xa); z01 += dot4(wa, xb);
    z10 += dot4(wb, xa); z11 += dot4(wb, xb);
  }
  const int b0 = base + bs, b1 = base + bs + 16;
  const float y0 = y[b0], y1 = y[b1];

  float p00 = 1.f/(1.f+expf(-z00)), p01 = 1.f/(1.f+expf(-z01));
  float p10 = 1.f/(1.f+expf(-z10)), p11 = 1.f/(1.f+expf(-z11));

  auto dzf = [](float p, float yv) {
    float pq = p - p*p;
    return pq*(yv - p)/(pq + 1e-8f);
  };
  float dz00 = dzf(p00, y0), dz01 = dzf(p01, y1);
  float dz10 = dzf(p10, y0), dz11 = dzf(p11, y1);

  // particle-axis reductions (32 particles = n0-fold + 16-lane xor tree)
  float sp0 = p00 + p10, sp1 = p01 + p11;
  float sd0 = dz00 + dz10, sd1 = dz01 + dz11;
  #pragma unroll
  for (int m = 8; m >= 1; m >>= 1) {
    sp0 += __shfl_xor(sp0, m); sp1 += __shfl_xor(sp1, m);
    sd0 += __shfl_xor(sd0, m); sd1 += __shfl_xor(sd1, m);
  }
  const float m0 = sd0*(1.f/32.f), m1 = sd1*(1.f/32.f);
  float q0 = (dz00-m0)*(dz00-m0) + (dz10-m0)*(dz10-m0);
  float q1 = (dz01-m1)*(dz01-m1) + (dz11-m1)*(dz11-m1);
  #pragma unroll
  for (int m = 8; m >= 1; m >>= 1) {
    q0 += __shfl_xor(q0, m); q1 += __shfl_xor(q1, m);
  }

  dzl[bs][n0]    = dz00; dzl[bs][n1]    = dz10;
  dzl[bs+16][n0] = dz01; dzl[bs+16][n1] = dz11;

  if (nb == 0) {
    s_ws[b0] = q0; s_ws[b1] = q1;
    float yp0 = sp0*(1.f/32.f), yp1 = sp1*(1.f/32.f);
    double ll = (double)(y0*logf(yp0+1e-3f) + (1.f-y0)*logf(1.f-yp0+1e-3f))
              + (double)(y1*logf(yp1+1e-3f) + (1.f-y1)*logf(1.f-yp1+1e-3f));
    float ac = (((y0 > 0.5f) == (yp0 > 0.5f)) ? 1.f : 0.f)
             + (((y1 > 0.5f) == (yp1 > 0.5f)) ? 1.f : 0.f);
    llred[bs] = ll; accred[bs] = ac;
  }
  __syncthreads();   // dzl + llred visible; Xl still resident

  // dW partial phase: dWp[blk][n][d] = sum_b dzl[b][n] * Xl[b][d]
  const int n = t >> 3, c = t & 7;
  float4 acc[8];
  #pragma unroll
  for (int m = 0; m < 8; ++m) acc[m] = make_float4(0.f,0.f,0.f,0.f);
  #pragma unroll 4
  for (int b = 0; b < 32; ++b) {
    float dzv = dzl[b][n];
    #pragma unroll
    for (int m = 0; m < 8; ++m) {
      float4 xv = Xl[b][c + 8*m];
      acc[m].x += dzv*xv.x; acc[m].y += dzv*xv.y;
      acc[m].z += dzv*xv.z; acc[m].w += dzv*xv.w;
    }
  }
  #pragma unroll
  for (int m = 0; m < 8; ++m)
    dWp4[blk*2048 + n*64 + c + 8*m] = acc[m];

  if (t == 0) {
    double L = 0.0;
    for (int i = 0; i < 16; ++i) L += llred[i];
    llpart[blk] = L;
  } else if (t == 1) {
    float A = 0.f;
    for (int i = 0; i < 16; ++i) A += accred[i];
    accpart[blk] = A;
  }
}

// ---------------------------------------------------------------------------
// K2: finalize W_grads = (sum_k dWpart) - W  (N_TRAIN/BATCH==1); ll/acc; tau=0
// ---------------------------------------------------------------------------
__global__ __launch_bounds__(256) void k_finalize(
    const float* __restrict__ dWpart, const float* __restrict__ W,
    float* __restrict__ Wg, const double* __restrict__ llpart,
    const float* __restrict__ accpart, float* __restrict__ out,
    unsigned int* __restrict__ tau_bits)
{
  const int blk = blockIdx.x, t = threadIdx.x;
  if (blk < 32) {
    float sum = 0.f;
    #pragma unroll 8
    for (int k = 0; k < 256; ++k) sum += dWpart[k*8192 + blk*256 + t];
    Wg[blk*256 + t] = sum - W[blk*256 + t];
  } else {
    if (t == 0) {
      double L = 0.0;
      for (int k = 0; k < 256; ++k) L += llpart[k];
      out[0] = (float)(L / 8192.0);
    } else if (t == 1) {
      float A = 0.f;
      for (int k = 0; k < 256; ++k) A += accpart[k];
      out[1] = A / 8192.f;
    } else if (t == 2) {
      *tau_bits = 0u;
    }
  }
}

// ---------------------------------------------------------------------------
// K3: cov partials, upper-triangle 64x64 tile-pairs only (cov is symmetric)
// grid (10,1,32) x 256; K-chunk 256 rows
// ---------------------------------------------------------------------------
__global__ __launch_bounds__(256) void k_cov(
    const float4* __restrict__ X4, const float* __restrict__ s_ws,
    float* __restrict__ covpart)
{
  __shared__ float4 Ad[32][17];
  __shared__ float4 Ae[32][17];
  const int t = threadIdx.x;
  const int p = blockIdx.x;
  const int dt = c_pi[p]*16;    // float4 units (64 floats)
  const int et = c_pj[p]*16;
  const int kb = blockIdx.z*256;
  const int tx = t & 15, ty = t >> 4;
  float acc[4][4];
  #pragma unroll
  for (int i = 0; i < 4; ++i)
    #pragma unroll
    for (int j = 0; j < 4; ++j) acc[i][j] = 0.f;

  for (int sub = 0; sub < 8; ++sub) {
    const int b0 = kb + sub*32;
    __syncthreads();
    #pragma unroll
    for (int i = 0; i < 2; ++i) {
      int idx = t + i*256; int row = idx>>4, c4 = idx&15;
      float sv = s_ws[b0+row];
      float4 xv = X4[(b0+row)*64 + dt + c4];
      Ad[row][c4] = make_float4(xv.x*sv, xv.y*sv, xv.z*sv, xv.w*sv);
      Ae[row][c4] = X4[(b0+row)*64 + et + c4];
    }
    __syncthreads();
    #pragma unroll 4
    for (int b = 0; b < 32; ++b) {
      float4 a = Ad[b][tx], e = Ae[b][ty];
      acc[0][0] += a.x*e.x; acc[0][1] += a.x*e.y; acc[0][2] += a.x*e.z; acc[0][3] += a.x*e.w;
      acc[1][0] += a.y*e.x; acc[1][1] += a.y*e.y; acc[1][2] += a.y*e.z; acc[1][3] += a.y*e.w;
      acc[2][0] += a.z*e.x; acc[2][1] += a.z*e.y; acc[2][2] += a.z*e.z; acc[2][3] += a.z*e.w;
      acc[3][0] += a.w*e.x; acc[3][1] += a.w*e.y; acc[3][2] += a.w*e.z; acc[3][3] += a.w*e.w;
    }
  }
  float4* cp4 = (float4*)(covpart + blockIdx.z*65536);
  #pragma unroll
  for (int i = 0; i < 4; ++i) {
    int gd = dt*4 + tx*4 + i;
    cp4[gd*64 + et + ty] = make_float4(acc[i][0], acc[i][1], acc[i][2], acc[i][3]);
  }
}

// ---------------------------------------------------------------------------
// K4: H = covsum/(32*8192) + 0.01 I (mirror-read lower tiles); tau via atomicMax
// ---------------------------------------------------------------------------
__global__ __launch_bounds__(256) void k_H(
    const float* __restrict__ covpart, float* __restrict__ H,
    unsigned int* __restrict__ tau_bits)
{
  __shared__ float red[4];
  const int d = blockIdx.x, t = threadIdx.x;
  const int td = d >> 6, te = t >> 6;
  const unsigned off = (td <= te) ? (unsigned)(d*256 + t) : (unsigned)(t*256 + d);
  float sum = 0.f;
  #pragma unroll 8
  for (int z = 0; z < 32; ++z) sum += covpart[z*65536u + off];
  float h = sum * (1.f/262144.f) + ((d == t) ? 0.01f : 0.f);
  H[d*256 + t] = h;
  float a = fabsf(h);
  #pragma unroll
  for (int m = 32; m >= 1; m >>= 1) a += __shfl_xor(a, m);
  if ((t & 63) == 0) red[t >> 6] = a;
  __syncthreads();
  if (t == 0) {
    float r = red[0] + red[1] + red[2] + red[3];
    atomicMax(tau_bits, __float_as_uint(r));   // order-independent -> deterministic
  }
}

// K5: E0 = I - alpha*H ; X0 = alpha*I  (alpha = 2/(tau+0.01))
__global__ __launch_bounds__(256) void k_nsinit(
    const unsigned int* __restrict__ tau_bits, const float* __restrict__ H,
    float* __restrict__ E0, float* __restrict__ X0)
{
  const float tau = __uint_as_float(*tau_bits);
  const float alpha = 2.f/(tau + 0.01f);
  const int d = blockIdx.x, t = threadIdx.x;
  const float h = H[d*256 + t];
  E0[d*256 + t] = ((d == t) ? 1.f : 0.f) - alpha*h;
  X0[d*256 + t] = (d == t) ? alpha : 0.f;
}

// ---------------------------------------------------------------------------
// K6: Newton-Schulz dual step (independent halves!):
//   blocks [0,64):   Enew = E@E
//   blocks [64,128): Xnew = X + X@E
// xonly=1: grid 64, all blocks do the X half (final step).
// 32x32 tile, 2x2 micro, transposed-A LDS for b64 reads.
// ---------------------------------------------------------------------------
__global__ __launch_bounds__(256) void k_nsdual(
    const float* __restrict__ E, const float* __restrict__ Xm,
    float* __restrict__ Enew, float* __restrict__ Xnew, int xonly)
{
  __shared__ float At[32][34];   // [kk][row], padded for 8B-aligned float2
  __shared__ float Bs[32][34];   // [kk][col]
  const int bb = blockIdx.x;
  const bool doX = xonly ? true : (bb >= 64);
  const int tileid = (xonly || bb < 64) ? bb : bb - 64;
  const float* __restrict__ A = doX ? Xm : E;

  const int t = threadIdx.x;
  const int i0 = (tileid >> 3)*32, j0 = (tileid & 7)*32;
  const int ti = t & 15, tj = t >> 4;
  const int srow = t >> 3, sc4 = t & 7;
  const float4* A4 = (const float4*)A;
  const float4* B4 = (const float4*)E;
  float acc00=0.f, acc01=0.f, acc10=0.f, acc11=0.f;

  for (int k0 = 0; k0 < 8; ++k0) {
    __syncthreads();
    float4 av = A4[(i0+srow)*64 + k0*8 + sc4];
    float4 bv = B4[(k0*32+srow)*64 + (j0>>2) + sc4];
    At[sc4*4+0][srow] = av.x; At[sc4*4+1][srow] = av.y;
    At[sc4*4+2][srow] = av.z; At[sc4*4+3][srow] = av.w;
    Bs[srow][sc4*4+0] = bv.x; Bs[srow][sc4*4+1] = bv.y;
    Bs[srow][sc4*4+2] = bv.z; Bs[srow][sc4*4+3] = bv.w;
    __syncthreads();
    #pragma unroll
    for (int kk = 0; kk < 32; ++kk) {
      float2 a = *(const float2*)&At[kk][2*ti];
      float2 b = *(const float2*)&Bs[kk][2*tj];
      acc00 += a.x*b.x; acc01 += a.x*b.y;
      acc10 += a.y*b.x; acc11 += a.y*b.y;
    }
  }
  const int gi = i0 + 2*ti, gj = j0 + 2*tj;
  if (doX) {
    Xnew[gi*256+gj]       = Xm[gi*256+gj]       + acc00;
    Xnew[gi*256+gj+1]     = Xm[gi*256+gj+1]     + acc01;
    Xnew[(gi+1)*256+gj]   = Xm[(gi+1)*256+gj]   + acc10;
    Xnew[(gi+1)*256+gj+1] = Xm[(gi+1)*256+gj+1] + acc11;
  } else {
    Enew[gi*256+gj]       = acc00; Enew[gi*256+gj+1]     = acc01;
    Enew[(gi+1)*256+gj]   = acc10; Enew[(gi+1)*256+gj+1] = acc11;
  }
}

// ---------------------------------------------------------------------------
// K7: RBF kernel + exact median (bitonic) + svgd_grad. 1 block x 1024
// ---------------------------------------------------------------------------
__global__ __launch_bounds__(1024) void k_rbf(
    const float4* __restrict__ W4, const float4* __restrict__ Wg4,
    float* __restrict__ svgd_ws, float* __restrict__ out)
{
  __shared__ float4 Wl[32][65];
  __shared__ float4 Wgl[32][65];
  __shared__ float pd[32][33];
  __shared__ float sb[1024];
  __shared__ float kx[32][33];
  __shared__ float sumk[32];
  __shared__ float hsh;
  const int t = threadIdx.x;

  #pragma unroll
  for (int i = 0; i < 2; ++i) {
    int idx = t + i*1024;
    Wl[idx>>6][idx&63]  = W4[idx];
    Wgl[idx>>6][idx&63] = Wg4[idx];
  }
  __syncthreads();

  const int i = t >> 5, j = t & 31;
  float d2 = 0.f;
  #pragma unroll 8
  for (int c = 0; c < 64; ++c) {
    float4 a = Wl[i][c], b = Wl[j][c];
    float dx=a.x-b.x, dy=a.y-b.y, dz=a.z-b.z, dw=a.w-b.w;
    d2 += dx*dx + dy*dy + dz*dz + dw*dw;
  }
  pd[i][j] = d2;
  sb[t] = d2;
  __syncthreads();

  for (int k = 2; k <= 1024; k <<= 1) {
    for (int jj = k >> 1; jj > 0; jj >>= 1) {
      int ixj = t ^ jj;
      if (ixj > t) {
        float a = sb[t], b = sb[ixj];
        bool up = ((t & k) == 0);
        if ((a > b) == up) { sb[t] = b; sb[ixj] = a; }
      }
      __syncthreads();
    }
  }
  if (t == 0) hsh = 0.5f*(sb[511] + sb[512]) / logf(33.0f);
  __syncthreads();
  const float h = hsh;

  float kv = expf(-pd[i][j]/h);
  kx[i][j] = kv;
  float sk = kv;
  #pragma unroll
  for (int m = 16; m >= 1; m >>= 1) sk += __shfl_xor(sk, m);
  if (j == 0) sumk[i] = sk;
  __syncthreads();

  const float c2 = 2.f/h;
  #pragma unroll
  for (int rep = 0; rep < 2; ++rep) {
    int o = t + rep*1024;
    int oi = o >> 6, oc = o & 63;
    float4 acc = make_float4(0.f,0.f,0.f,0.f);
    #pragma unroll 4
    for (int jj = 0; jj < 32; ++jj) {
      float kvv = kx[oi][jj];
      float4 wg = Wgl[jj][oc], w = Wl[jj][oc];
      acc.x += kvv*(wg.x - c2*w.x);
      acc.y += kvv*(wg.y - c2*w.y);
      acc.z += kvv*(wg.z - c2*w.z);
      acc.w += kvv*(wg.w - c2*w.w);
    }
    float4 wi = Wl[oi][oc];
    float s = c2 * sumk[oi];
    acc.x = (acc.x + s*wi.x) * (1.f/32.f);
    acc.y = (acc.y + s*wi.y) * (1.f/32.f);
    acc.z = (acc.z + s*wi.z) * (1.f/32.f);
    acc.w = (acc.w + s*wi.w) * (1.f/32.f);
    ((float4*)svgd_ws)[oi*64 + oc] = acc;
    int base = 2 + oi*256 + oc*4;     // d_out+2 only 8B aligned -> scalar stores
    out[base+0] = acc.x; out[base+1] = acc.y; out[base+2] = acc.z; out[base+3] = acc.w;
  }
}

// ---------------------------------------------------------------------------
// K8: kfac = svgd @ Hinv
// ---------------------------------------------------------------------------
__global__ __launch_bounds__(256) void k_kfac(
    const float* __restrict__ svgd, const float* __restrict__ Hinv,
    float* __restrict__ out)
{
  __shared__ float sv[256];
  const int i = blockIdx.x, t = threadIdx.x;
  sv[t] = svgd[i*256 + t];
  __syncthreads();
  float acc = 0.f;
  #pragma unroll 8
  for (int k = 0; k < 256; ++k) acc += sv[k] * Hinv[k*256 + t];
  out[2 + 8192 + i*256 + t] = acc;
}

// ---------------------------------------------------------------------------
extern "C" void kernel_launch(void* const* d_in, const int* in_sizes, int n_in,
                              void* d_out, int out_size, void* d_ws, size_t ws_size,
                              hipStream_t stream) {
  (void)in_sizes; (void)n_in; (void)out_size; (void)ws_size;
  const float* X = (const float*)d_in[0];
  const float* y = (const float*)d_in[1];
  const float* W = (const float*)d_in[2];
  float* out = (float*)d_out;
  float* ws  = (float*)d_ws;

  float* s_ws  = ws + OFF_S;
  float* dWp   = ws + OFF_DWP;
  float* Wg    = ws + OFF_WG;
  float* covp  = ws + OFF_COVP;
  float* H     = ws + OFF_H;
  float* EA    = ws + OFF_EA;
  float* EB    = ws + OFF_EB;
  float* XA    = ws + OFF_XA;
  float* XB    = ws + OFF_XB;
  float* svgd  = ws + OFF_SVGD;
  double* llp  = (double*)(ws + OFF_LLP);
  float* accp  = ws + OFF_ACCP;
  unsigned int* tau = (unsigned int*)(ws + OFF_TAU);

  k_fused1<<<256, 256, 0, stream>>>((const float4*)X, y, (const float4*)W,
                                    s_ws, (float4*)dWp, llp, accp);
  k_finalize<<<33, 256, 0, stream>>>(dWp, W, Wg, llp, accp, out, tau);
  k_rbf<<<1, 1024, 0, stream>>>((const float4*)W, (const float4*)Wg, svgd, out);
  k_cov<<<dim3(10,1,32), 256, 0, stream>>>((const float4*)X, s_ws, covp);
  k_H<<<256, 256, 0, stream>>>(covp, H, tau);
  k_nsinit<<<256, 256, 0, stream>>>(tau, H, EA, XA);

  // Newton-Schulz: 8 squarings -> residual eps0^256 (eps0 ~= 0.87 expected)
  float *Ec = EA, *En = EB, *Xc = XA, *Xn = XB;
  for (int j = 0; j < 7; ++j) {
    k_nsdual<<<128, 256, 0, stream>>>(Ec, Xc, En, Xn, 0);
    float* tE = Ec; Ec = En; En = tE;
    float* tX = Xc; Xc = Xn; Xn = tX;
  }
  k_nsdual<<<64, 256, 0, stream>>>(Ec, Xc, En, Xn, 1);   // final: X-half only
  Xc = Xn;

  k_kfac<<<32, 256, 0, stream>>>(svgd, Xc, out);
}